// Round 6
// baseline (163.029 us; speedup 1.0000x reference)
//
#include <hip/hip_runtime.h>
#include <hip/hip_bf16.h>
#include <stdint.h>

#define BATCH 1024
#define IN_DIM 784
#define NHEADS 10
#define NCOL 640          // 10 heads * 64 out
#define NB 9              // 8 basis + silu
#define KRED (IN_DIM*NB)  // 7056
#define KPAD 7168         // padded to multiple of 64
#define SK 8
#define KCHUNK (KPAD/SK)  // 896
#define BK 64
#define KITERS (KCHUNK/BK) // 14
#define BM 128
#define BN 64
#define TILES 80          // 8 bm x 10 bn
#define ABUF (BM*BK)      // 8192 ushorts per A buffer
#define BBUF (BN*BK)      // 4096 ushorts per B buffer

typedef __bf16 v8bf __attribute__((ext_vector_type(8)));
typedef float  v4f  __attribute__((ext_vector_type(4)));

static __device__ __forceinline__ unsigned short f2bf(float f) {
    __hip_bfloat16 h = __float2bfloat16(f);
    return __builtin_bit_cast(unsigned short, h);
}

// ---- kernel 1 (fused prep): blocks [0,1024) build A features; [1024,1514) build Wt ----
// Also zeroes the split-K arrival counters (block 0) -- must precede gemm (stream order).
__global__ __launch_bounds__(256) void prep_kernel(const float* __restrict__ x,
                                                   const float* __restrict__ coef,
                                                   const float* __restrict__ sb,
                                                   const float* __restrict__ ssp,
                                                   const float* __restrict__ lmd,
                                                   unsigned short* __restrict__ A,
                                                   unsigned short* __restrict__ Wt,
                                                   int* __restrict__ cnt) {
    __shared__ unsigned short LS[64 * 144];     // 18432 B (feat path uses first 14336 B)
    const int t = threadIdx.x;
    if (blockIdx.x == 0 && t < TILES) cnt[t] = 0;
    if (blockIdx.x < BATCH) {
        const int b = blockIdx.x;
#pragma unroll
        for (int p = 0; p < 4; ++p) {
            int i = p * 256 + t;
            if (i < IN_DIM) {
                float xv = x[b * IN_DIM + i];
                float s = xv * 5.0f;
                int m0 = (int)s; m0 = m0 < 0 ? 0 : (m0 > 4 ? 4 : m0);
                float tt = s - (float)m0;
                float omt = 1.0f - tt, t2 = tt * tt, t3 = t2 * tt;
                float c0 = omt * omt * omt * (1.0f / 6.0f);
                float c1 = (3.0f * t3 - 6.0f * t2 + 4.0f) * (1.0f / 6.0f);
                float c2 = (-3.0f * t3 + 3.0f * t2 + 3.0f * tt + 1.0f) * (1.0f / 6.0f);
                float c3 = t3 * (1.0f / 6.0f);
                float sil = xv / (1.0f + expf(-xv));
                unsigned short* f = LS + i * NB;
#pragma unroll
                for (int k = 0; k < 8; ++k) {
                    int d = k - m0;
                    float v = (d == 0) ? c0 : (d == 1) ? c1 : (d == 2) ? c2 : (d == 3) ? c3 : 0.0f;
                    f[k] = f2bf(v);
                }
                f[8] = f2bf(sil);
            }
        }
        if (t < KPAD - KRED) LS[KRED + t] = 0;   // K padding
        __syncthreads();
        uint4* dst = (uint4*)(A + (size_t)b * KPAD);
        const uint4* srcv = (const uint4*)LS;
#pragma unroll
        for (int j = 0; j < 4; ++j) {            // 7168 ushorts = 896 x 16B
            int idx = j * 256 + t;
            if (idx < 896) dst[idx] = srcv[idx];
        }
    } else {
        const int blk = blockIdx.x - BATCH;      // 0..489
        const int h = blk / 49, ic = blk % 49;
        const int o = t & 63, iq = t >> 6;
#pragma unroll
        for (int ip = 0; ip < 4; ++ip) {
            int il = iq * 4 + ip;                // 0..15
            int i = ic * 16 + il;
            int hi = h * IN_DIM + i;
            float lm  = lmd[hi];
            float spv = ssp[(size_t)hi * 64 + o] * lm;
            float bse = sb [(size_t)hi * 64 + o] * lm;
            const float* cp = coef + ((size_t)hi * 64 + o) * 8;   // 32B contiguous, lanes span o
            unsigned short* d = LS + o * 144 + il * 9;
#pragma unroll
            for (int k = 0; k < 8; ++k) d[k] = f2bf(cp[k] * spv);
            d[8] = f2bf(bse);
        }
        __syncthreads();
#pragma unroll
        for (int j = 0; j < 5; ++j) {            // 64 rows x 288B = 1152 x 16B
            int idx = j * 256 + t;
            if (idx < 1152) {
                int row = idx / 18, c = idx - row * 18;
                uint4 v = *(const uint4*)(LS + row * 144 + c * 8);
                *(uint4*)(Wt + (size_t)(h * 64 + row) * KPAD + ic * 144 + c * 8) = v;
            }
        }
        if (ic == 48) {                          // zero K-pad: 64 rows x 224B = 896 x 16B
            uint4 z = uint4{0, 0, 0, 0};
#pragma unroll
            for (int j = 0; j < 4; ++j) {
                int idx = j * 256 + t;
                if (idx < 896) {
                    int row = idx / 14, c = idx - row * 14;
                    *(uint4*)(Wt + (size_t)(h * 64 + row) * KPAD + KRED + c * 8) = z;
                }
            }
        }
    }
}

// ---- kernel 2: GEMM (128x64 tile, 4 waves, split-K=8) + FUSED split-K reduce/MLP ----
// 640 blocks; XCD x (= p%8 round-robin) owns split-K slice x. Ping-pong dbuf.
// After the C-write, each block fences + bumps cnt[tile]; the 8th arrival re-reads
// the 8 P-slices for its tile (one head x 128 batch rows -- BN=64 = head-aligned),
// and runs the whole epilogue (tanh -> 64x32 MLP -> tanh -> dot W2) using the
// now-free As/Bs LDS. Deterministic: reduction order fixed (sk=0..7), only the
// reducer's identity varies.
__global__ __launch_bounds__(256) void gemm_kernel(const unsigned short* __restrict__ A,
                                                   const unsigned short* __restrict__ Wt,
                                                   float* __restrict__ P,
                                                   const float* __restrict__ W1,
                                                   const float* __restrict__ b1,
                                                   const float* __restrict__ W2,
                                                   const float* __restrict__ b2,
                                                   float* __restrict__ out,
                                                   int* __restrict__ cnt) {
    __shared__ unsigned short As[2 * ABUF];      // 32 KB
    __shared__ unsigned short Bs[2 * BBUF];      // 16 KB
    __shared__ int lastFlag;
    const int p = blockIdx.x;
    const int sk = p & 7;                        // XCD x owns split-K slice x
    const int rem = p >> 3;                      // tile id 0..79
    const int bn = rem >> 3;                     // 0..9 (= head)
    const int bm = rem & 7;                      // 0..7
    const int tid = threadIdx.x;
    const int w = tid >> 6, l = tid & 63;

    v4f acc[2][4];
#pragma unroll
    for (int a = 0; a < 2; ++a)
#pragma unroll
        for (int b = 0; b < 4; ++b) acc[a][b] = v4f{0.f, 0.f, 0.f, 0.f};

    const int k0 = sk * KCHUNK;
    const int arow0 = w * 32 + (l & 15);
    const int kkb = (l >> 4) * 16;               // byte offset of lane's 16B within 128B row

#define STAGE(buf, kc)                                                                   \
    {                                                                                    \
        _Pragma("unroll")                                                                \
        for (int r = 0; r < 4; ++r) {            /* A: 128 rows x 128B = 1024 chunks */  \
            int L = r * 256 + tid;                                                       \
            int row = L >> 3, scc = ((L & 7) ^ (row & 7)) * 8;                           \
            __builtin_amdgcn_global_load_lds(                                            \
                (const __attribute__((address_space(1))) void*)(A +                      \
                    (size_t)(bm * BM + row) * KPAD + (kc) + scc),                        \
                (__attribute__((address_space(3))) void*)(As + (buf) * ABUF +            \
                    (r * 256 + w * 64) * 8), 16, 0, 0);                                  \
        }                                                                                \
        _Pragma("unroll")                                                                \
        for (int r = 0; r < 2; ++r) {            /* B: 64 rows x 128B = 512 chunks */    \
            int L = r * 256 + tid;                                                       \
            int row = L >> 3, scc = ((L & 7) ^ (row & 7)) * 8;                           \
            __builtin_amdgcn_global_load_lds(                                            \
                (const __attribute__((address_space(1))) void*)(Wt +                     \
                    (size_t)(bn * BN + row) * KPAD + (kc) + scc),                        \
                (__attribute__((address_space(3))) void*)(Bs + (buf) * BBUF +            \
                    (r * 256 + w * 64) * 8), 16, 0, 0);                                  \
        }                                                                                \
    }

#define COMPUTE(buf)                                                                     \
    {                                                                                    \
        const char* Ab = (const char*)(As + (buf) * ABUF);                               \
        const char* Bb = (const char*)(Bs + (buf) * BBUF);                               \
        _Pragma("unroll")                                                                \
        for (int ks = 0; ks < 2; ++ks) {                                                 \
            v8bf af[2], bfr[4];                                                          \
            _Pragma("unroll")                                                            \
            for (int f = 0; f < 2; ++f) {                                                \
                int ar = arow0 + f * 16;                                                 \
                af[f] = *(const v8bf*)(Ab + ((ar * 128 + ks * 64 + kkb) ^ ((ar & 7) << 4))); \
            }                                                                            \
            _Pragma("unroll")                                                            \
            for (int g = 0; g < 4; ++g) {                                                \
                int br = g * 16 + (l & 15);                                              \
                bfr[g] = *(const v8bf*)(Bb + ((br * 128 + ks * 64 + kkb) ^ ((br & 7) << 4))); \
            }                                                                            \
            _Pragma("unroll")                                                            \
            for (int fi = 0; fi < 2; ++fi)                                               \
                _Pragma("unroll")                                                        \
                for (int fj = 0; fj < 4; ++fj)                                           \
                    acc[fi][fj] = __builtin_amdgcn_mfma_f32_16x16x32_bf16(               \
                        af[fi], bfr[fj], acc[fi][fj], 0, 0, 0);                          \
        }                                                                                \
    }

    STAGE(0, k0);
    __syncthreads();
#pragma unroll 1
    for (int t2 = 0; t2 < KITERS / 2; ++t2) {    // 7 double-iterations
        STAGE(1, k0 + (2 * t2 + 1) * BK);
        COMPUTE(0);
        __syncthreads();
        if (t2 + 1 < KITERS / 2) STAGE(0, k0 + (2 * t2 + 2) * BK);
        COMPUTE(1);
        __syncthreads();
    }
#undef STAGE
#undef COMPUTE

    // C/D layout: col = lane&15, row = 4*(lane>>4)+r   [measured m89]
    const int rowb = bm * BM + w * 32 + 4 * (l >> 4);
    const int colb = bn * BN + (l & 15);
#pragma unroll
    for (int fi = 0; fi < 2; ++fi)
#pragma unroll
        for (int fj = 0; fj < 4; ++fj)
#pragma unroll
            for (int r = 0; r < 4; ++r)
                P[((size_t)sk * BATCH + rowb + fi * 16 + r) * NCOL + colb + fj * 16] =
                    acc[fi][fj][r];

    // ---- fused split-K reduction + epilogue (threadfence-reduction pattern) ----
    __threadfence();                             // make this thread's P stores visible
    __syncthreads();                             // all block stores fenced
    if (tid == 0) lastFlag = (atomicAdd(&cnt[rem], 1) == SK - 1);
    __syncthreads();
    if (!lastFlag) return;
    __threadfence();                             // acquire: see the other 7 slices

    const int h = bn;
    float* h1s = (float*)As;                     // 128 x 64 fp32 = 32 KB
    float* W1s = (float*)Bs;                     // 64 x 32 fp32 = 8 KB
    for (int j = tid; j < 64 * 32; j += 256) W1s[j] = W1[h * 2048 + j];
    {
        const int o = tid & 63, rq = tid >> 6;
#pragma unroll 4
        for (int pass = 0; pass < 32; ++pass) {
            int r = pass * 4 + rq;
            float y = 0.f;
#pragma unroll
            for (int s = 0; s < SK; ++s)
                y += P[((size_t)s * BATCH + bm * BM + r) * NCOL + h * 64 + o];
            h1s[r * 64 + o] = tanhf(y);
        }
    }
    __syncthreads();
    {
        const int d = tid & 31;
        const float w2v = W2[h * 32 + d];
        const float b1v = b1[h * 32 + d];
        const float b2v = b2[h];
#pragma unroll 2
        for (int pass = 0; pass < 16; ++pass) {
            int r = pass * 8 + (tid >> 5);
            float a2 = 0.f;
#pragma unroll 8
            for (int o2 = 0; o2 < 64; ++o2) a2 += h1s[r * 64 + o2] * W1s[o2 * 32 + d];
            float h2 = tanhf(a2 + b1v);
            float pp = h2 * w2v;
#pragma unroll
            for (int off = 16; off; off >>= 1) pp += __shfl_xor(pp, off);
            if (d == 0) out[(bm * BM + r) * NHEADS + h] = pp + b2v;
        }
    }
}

extern "C" void kernel_launch(void* const* d_in, const int* in_sizes, int n_in,
                              void* d_out, int out_size, void* d_ws, size_t ws_size,
                              hipStream_t stream) {
    const float* x    = (const float*)d_in[0];
    const float* coef = (const float*)d_in[1];
    const float* sb   = (const float*)d_in[2];
    const float* ssp  = (const float*)d_in[3];
    const float* lmd  = (const float*)d_in[4];
    const float* W1   = (const float*)d_in[5];
    const float* b1   = (const float*)d_in[6];
    const float* W2   = (const float*)d_in[7];
    const float* b2   = (const float*)d_in[8];
    float* out = (float*)d_out;

    unsigned short* Af = (unsigned short*)d_ws;                  // 1024*7168*2 = 14.68 MB
    unsigned short* Wt = Af + (size_t)BATCH * KPAD;              // 640*7168*2  =  9.18 MB
    float* P = (float*)(Wt + (size_t)NCOL * KPAD);               // 8*1024*640*4 = 20.97 MB
    int* cnt = (int*)(P + (size_t)SK * BATCH * NCOL);            // 80 ints

    hipLaunchKernelGGL(prep_kernel, dim3(BATCH + 490), dim3(256), 0, stream,
                       x, coef, sb, ssp, lmd, Af, Wt, cnt);
    hipLaunchKernelGGL(gemm_kernel, dim3(640), dim3(256), 0, stream,
                       Af, Wt, P, W1, b1, W2, b2, out, cnt);
}

// Round 7
// 42.914 us; speedup vs baseline: 3.7989x; 3.7989x over previous
//
#include <hip/hip_runtime.h>
#include <hip/hip_bf16.h>
#include <stdint.h>

#define BATCH 1024
#define IN_DIM 784
#define NHEADS 10
#define NCOL 640          // 10 heads * 64 out
#define NB 9              // 8 basis + silu
#define KRED (IN_DIM*NB)  // 7056
#define KPAD 7168         // padded to multiple of 64
#define SK 8
#define KCHUNK (KPAD/SK)  // 896
#define BK 64
#define KITERS (KCHUNK/BK) // 14
#define BM 128
#define BN 64
#define ABUF (BM*BK)      // 8192 ushorts per A buffer
#define BBUF (BN*BK)      // 4096 ushorts per B buffer

typedef __bf16 v8bf __attribute__((ext_vector_type(8)));
typedef float  v4f  __attribute__((ext_vector_type(4)));

static __device__ __forceinline__ unsigned short f2bf(float f) {
    __hip_bfloat16 h = __float2bfloat16(f);
    return __builtin_bit_cast(unsigned short, h);
}
static __device__ __forceinline__ float bf2f(unsigned short u) {
    return __builtin_bit_cast(float, (uint32_t)u << 16);
}

// ---- kernel 1 (fused prep): blocks [0,1024) build A features; [1024,1514) build Wt ----
__global__ __launch_bounds__(256) void prep_kernel(const float* __restrict__ x,
                                                   const float* __restrict__ coef,
                                                   const float* __restrict__ sb,
                                                   const float* __restrict__ ssp,
                                                   const float* __restrict__ lmd,
                                                   unsigned short* __restrict__ A,
                                                   unsigned short* __restrict__ Wt) {
    __shared__ unsigned short LS[64 * 144];     // 18432 B (feat path uses first 14336 B)
    const int t = threadIdx.x;
    if (blockIdx.x < BATCH) {
        const int b = blockIdx.x;
#pragma unroll
        for (int p = 0; p < 4; ++p) {
            int i = p * 256 + t;
            if (i < IN_DIM) {
                float xv = x[b * IN_DIM + i];
                float s = xv * 5.0f;
                int m0 = (int)s; m0 = m0 < 0 ? 0 : (m0 > 4 ? 4 : m0);
                float tt = s - (float)m0;
                float omt = 1.0f - tt, t2 = tt * tt, t3 = t2 * tt;
                float c0 = omt * omt * omt * (1.0f / 6.0f);
                float c1 = (3.0f * t3 - 6.0f * t2 + 4.0f) * (1.0f / 6.0f);
                float c2 = (-3.0f * t3 + 3.0f * t2 + 3.0f * tt + 1.0f) * (1.0f / 6.0f);
                float c3 = t3 * (1.0f / 6.0f);
                float sil = xv / (1.0f + expf(-xv));
                unsigned short* f = LS + i * NB;
#pragma unroll
                for (int k = 0; k < 8; ++k) {
                    int d = k - m0;
                    float v = (d == 0) ? c0 : (d == 1) ? c1 : (d == 2) ? c2 : (d == 3) ? c3 : 0.0f;
                    f[k] = f2bf(v);
                }
                f[8] = f2bf(sil);
            }
        }
        if (t < KPAD - KRED) LS[KRED + t] = 0;   // K padding
        __syncthreads();
        uint4* dst = (uint4*)(A + (size_t)b * KPAD);
        const uint4* srcv = (const uint4*)LS;
#pragma unroll
        for (int j = 0; j < 4; ++j) {            // 7168 ushorts = 896 x 16B
            int idx = j * 256 + t;
            if (idx < 896) dst[idx] = srcv[idx];
        }
    } else {
        const int blk = blockIdx.x - BATCH;      // 0..489
        const int h = blk / 49, ic = blk % 49;
        const int o = t & 63, iq = t >> 6;
#pragma unroll
        for (int ip = 0; ip < 4; ++ip) {
            int il = iq * 4 + ip;                // 0..15
            int i = ic * 16 + il;
            int hi = h * IN_DIM + i;
            float lm  = lmd[hi];
            float spv = ssp[(size_t)hi * 64 + o] * lm;
            float bse = sb [(size_t)hi * 64 + o] * lm;
            const float* cp = coef + ((size_t)hi * 64 + o) * 8;   // 32B contiguous, lanes span o
            unsigned short* d = LS + o * 144 + il * 9;
#pragma unroll
            for (int k = 0; k < 8; ++k) d[k] = f2bf(cp[k] * spv);
            d[8] = f2bf(bse);
        }
        __syncthreads();
#pragma unroll
        for (int j = 0; j < 5; ++j) {            // 64 rows x 288B = 1152 x 16B
            int idx = j * 256 + t;
            if (idx < 1152) {
                int row = idx / 18, c = idx - row * 18;
                uint4 v = *(const uint4*)(LS + row * 144 + c * 8);
                *(uint4*)(Wt + (size_t)(h * 64 + row) * KPAD + ic * 144 + c * 8) = v;
            }
        }
        if (ic == 48) {                          // zero K-pad: 64 rows x 224B = 896 x 16B
            uint4 z = uint4{0, 0, 0, 0};
#pragma unroll
            for (int j = 0; j < 4; ++j) {
                int idx = j * 256 + t;
                if (idx < 896) {
                    int row = idx / 14, c = idx - row * 14;
                    *(uint4*)(Wt + (size_t)(h * 64 + row) * KPAD + KRED + c * 8) = z;
                }
            }
        }
    }
}

// ---- kernel 2: GEMM 1024x640x7168 bf16 MFMA, tile 128x64, 4 waves, split-K=8 ----
// Round-4 structure (best known: 43.9us total). Partials P stored as bf16
// (halves P write+read traffic; tanh saturation + 1/8-scale W1 absorb the error).
__global__ __launch_bounds__(256) void gemm_kernel(const unsigned short* __restrict__ A,
                                                   const unsigned short* __restrict__ Wt,
                                                   unsigned short* __restrict__ P) {
    __shared__ unsigned short As[2 * ABUF];      // 32 KB
    __shared__ unsigned short Bs[2 * BBUF];      // 16 KB
    const int p = blockIdx.x;
    const int sk = p & 7;                        // XCD x owns split-K slice x
    const int rem = p >> 3;
    const int bn = rem >> 3;                     // 0..9
    const int bm = rem & 7;                      // 0..7
    const int tid = threadIdx.x;
    const int w = tid >> 6, l = tid & 63;

    v4f acc[2][4];
#pragma unroll
    for (int a = 0; a < 2; ++a)
#pragma unroll
        for (int b = 0; b < 4; ++b) acc[a][b] = v4f{0.f, 0.f, 0.f, 0.f};

    const int k0 = sk * KCHUNK;
    const int arow0 = w * 32 + (l & 15);
    const int kkb = (l >> 4) * 16;               // byte offset of lane's 16B within 128B row

#define STAGE(buf, kc)                                                                   \
    {                                                                                    \
        _Pragma("unroll")                                                                \
        for (int r = 0; r < 4; ++r) {            /* A: 128 rows x 128B = 1024 chunks */  \
            int L = r * 256 + tid;                                                       \
            int row = L >> 3, scc = ((L & 7) ^ (row & 7)) * 8;                           \
            __builtin_amdgcn_global_load_lds(                                            \
                (const __attribute__((address_space(1))) void*)(A +                      \
                    (size_t)(bm * BM + row) * KPAD + (kc) + scc),                        \
                (__attribute__((address_space(3))) void*)(As + (buf) * ABUF +            \
                    (r * 256 + w * 64) * 8), 16, 0, 0);                                  \
        }                                                                                \
        _Pragma("unroll")                                                                \
        for (int r = 0; r < 2; ++r) {            /* B: 64 rows x 128B = 512 chunks */    \
            int L = r * 256 + tid;                                                       \
            int row = L >> 3, scc = ((L & 7) ^ (row & 7)) * 8;                           \
            __builtin_amdgcn_global_load_lds(                                            \
                (const __attribute__((address_space(1))) void*)(Wt +                     \
                    (size_t)(bn * BN + row) * KPAD + (kc) + scc),                        \
                (__attribute__((address_space(3))) void*)(Bs + (buf) * BBUF +            \
                    (r * 256 + w * 64) * 8), 16, 0, 0);                                  \
        }                                                                                \
    }

#define COMPUTE(buf)                                                                     \
    {                                                                                    \
        const char* Ab = (const char*)(As + (buf) * ABUF);                               \
        const char* Bb = (const char*)(Bs + (buf) * BBUF);                               \
        _Pragma("unroll")                                                                \
        for (int ks = 0; ks < 2; ++ks) {                                                 \
            v8bf af[2], bfr[4];                                                          \
            _Pragma("unroll")                                                            \
            for (int f = 0; f < 2; ++f) {                                                \
                int ar = arow0 + f * 16;                                                 \
                af[f] = *(const v8bf*)(Ab + ((ar * 128 + ks * 64 + kkb) ^ ((ar & 7) << 4))); \
            }                                                                            \
            _Pragma("unroll")                                                            \
            for (int g = 0; g < 4; ++g) {                                                \
                int br = g * 16 + (l & 15);                                              \
                bfr[g] = *(const v8bf*)(Bb + ((br * 128 + ks * 64 + kkb) ^ ((br & 7) << 4))); \
            }                                                                            \
            _Pragma("unroll")                                                            \
            for (int fi = 0; fi < 2; ++fi)                                               \
                _Pragma("unroll")                                                        \
                for (int fj = 0; fj < 4; ++fj)                                           \
                    acc[fi][fj] = __builtin_amdgcn_mfma_f32_16x16x32_bf16(               \
                        af[fi], bfr[fj], acc[fi][fj], 0, 0, 0);                          \
        }                                                                                \
    }

    STAGE(0, k0);
    __syncthreads();
#pragma unroll 1
    for (int t2 = 0; t2 < KITERS / 2; ++t2) {    // 7 double-iterations
        STAGE(1, k0 + (2 * t2 + 1) * BK);
        COMPUTE(0);
        __syncthreads();
        if (t2 + 1 < KITERS / 2) STAGE(0, k0 + (2 * t2 + 2) * BK);
        COMPUTE(1);
        __syncthreads();
    }
#undef STAGE
#undef COMPUTE

    // C/D layout: col = lane&15, row = 4*(lane>>4)+r   [measured m89]
    const int rowb = bm * BM + w * 32 + 4 * (l >> 4);
    const int colb = bn * BN + (l & 15);
#pragma unroll
    for (int fi = 0; fi < 2; ++fi)
#pragma unroll
        for (int fj = 0; fj < 4; ++fj)
#pragma unroll
            for (int r = 0; r < 4; ++r)
                P[((size_t)sk * BATCH + rowb + fi * 16 + r) * NCOL + colb + fj * 16] =
                    f2bf(acc[fi][fj][r]);
}

// ---- kernel 3: reduce split-K (bf16 partials) + tanh + per-head MLP ----
__global__ void epi_kernel(const unsigned short* __restrict__ P, const float* __restrict__ W1,
                           const float* __restrict__ b1, const float* __restrict__ W2,
                           const float* __restrict__ b2, float* __restrict__ out) {
    int wid = blockIdx.x * 4 + (threadIdx.x >> 6);   // one wave per (b,h)
    int lane = threadIdx.x & 63;
    int b = wid / NHEADS, h = wid % NHEADS;
    float y = 0.0f;
    size_t base = (size_t)b * NCOL + h * 64 + lane;  // o = lane
#pragma unroll
    for (int s = 0; s < SK; ++s) y += bf2f(P[(size_t)s * BATCH * NCOL + base]);
    float h1 = tanhf(y);
    int d = lane & 31;
    float a2 = 0.0f;
#pragma unroll 8
    for (int o = 0; o < 64; ++o) {
        float ho = __shfl(h1, o);
        a2 += ho * W1[(h * 64 + o) * 32 + d];
    }
    float h2 = tanhf(a2 + b1[h * 32 + d]);
    float part = (lane < 32) ? h2 * W2[h * 32 + d] : 0.0f;
#pragma unroll
    for (int off = 32; off; off >>= 1) part += __shfl_xor(part, off);
    if (lane == 0) out[b * NHEADS + h] = part + b2[h];
}

extern "C" void kernel_launch(void* const* d_in, const int* in_sizes, int n_in,
                              void* d_out, int out_size, void* d_ws, size_t ws_size,
                              hipStream_t stream) {
    const float* x    = (const float*)d_in[0];
    const float* coef = (const float*)d_in[1];
    const float* sb   = (const float*)d_in[2];
    const float* ssp  = (const float*)d_in[3];
    const float* lmd  = (const float*)d_in[4];
    const float* W1   = (const float*)d_in[5];
    const float* b1   = (const float*)d_in[6];
    const float* W2   = (const float*)d_in[7];
    const float* b2   = (const float*)d_in[8];
    float* out = (float*)d_out;

    unsigned short* Af = (unsigned short*)d_ws;                  // 1024*7168*2 = 14.68 MB
    unsigned short* Wt = Af + (size_t)BATCH * KPAD;              // 640*7168*2  =  9.18 MB
    unsigned short* P  = Wt + (size_t)NCOL * KPAD;               // 8*1024*640*2 = 10.49 MB

    hipLaunchKernelGGL(prep_kernel, dim3(BATCH + 490), dim3(256), 0, stream,
                       x, coef, sb, ssp, lmd, Af, Wt);
    hipLaunchKernelGGL(gemm_kernel, dim3(640), dim3(256), 0, stream, Af, Wt, P);
    hipLaunchKernelGGL(epi_kernel, dim3(2560), dim3(256), 0, stream, P, W1, b1, W2, b2, out);
}

// Round 8
// 36.284 us; speedup vs baseline: 4.4931x; 1.1827x over previous
//
#include <hip/hip_runtime.h>
#include <hip/hip_bf16.h>
#include <stdint.h>

#define BATCH 1024
#define IN_DIM 784
#define NHEADS 10
#define NCOL 640          // 10 heads * 64 out
#define NB 9              // 8 basis + silu
#define KRED (IN_DIM*NB)  // 7056
#define KPAD 7168         // padded to multiple of 64
#define SK 8
#define KCHUNK (KPAD/SK)  // 896
#define BK 64
#define KITERS (KCHUNK/BK) // 14
#define BM 128
#define BN 64
#define ABUF (BM*BK)      // 8192 ushorts per A buffer
#define BBUF (BN*BK)      // 4096 ushorts per B buffer

typedef __bf16 v8bf __attribute__((ext_vector_type(8)));
typedef float  v4f  __attribute__((ext_vector_type(4)));

static __device__ __forceinline__ unsigned short f2bf(float f) {
    __hip_bfloat16 h = __float2bfloat16(f);
    return __builtin_bit_cast(unsigned short, h);
}
static __device__ __forceinline__ float bf2f(unsigned short u) {
    return __builtin_bit_cast(float, (uint32_t)u << 16);
}

// ---- kernel 1 (fused prep): blocks [0,1024) build A features; [1024,1514) build Wt ----
__global__ __launch_bounds__(256) void prep_kernel(const float* __restrict__ x,
                                                   const float* __restrict__ coef,
                                                   const float* __restrict__ sb,
                                                   const float* __restrict__ ssp,
                                                   const float* __restrict__ lmd,
                                                   unsigned short* __restrict__ A,
                                                   unsigned short* __restrict__ Wt) {
    __shared__ unsigned short LS[64 * 144];     // 18432 B (feat path uses first 14336 B)
    const int t = threadIdx.x;
    if (blockIdx.x < BATCH) {
        const int b = blockIdx.x;
        if (t < 196) {                           // 196 float4 = 784 x-values
            float4 xv4 = ((const float4*)(x + (size_t)b * IN_DIM))[t];
#pragma unroll
            for (int j = 0; j < 4; ++j) {
                int i = t * 4 + j;
                float xv = j == 0 ? xv4.x : j == 1 ? xv4.y : j == 2 ? xv4.z : xv4.w;
                float s = xv * 5.0f;
                int m0 = (int)s; m0 = m0 < 0 ? 0 : (m0 > 4 ? 4 : m0);
                float tt = s - (float)m0;
                float omt = 1.0f - tt, t2 = tt * tt, t3 = t2 * tt;
                float c0 = omt * omt * omt * (1.0f / 6.0f);
                float c1 = (3.0f * t3 - 6.0f * t2 + 4.0f) * (1.0f / 6.0f);
                float c2 = (-3.0f * t3 + 3.0f * t2 + 3.0f * tt + 1.0f) * (1.0f / 6.0f);
                float c3 = t3 * (1.0f / 6.0f);
                float sil = xv / (1.0f + expf(-xv));
                unsigned short* f = LS + i * NB;
#pragma unroll
                for (int k = 0; k < 8; ++k) {
                    int d = k - m0;
                    float v = (d == 0) ? c0 : (d == 1) ? c1 : (d == 2) ? c2 : (d == 3) ? c3 : 0.0f;
                    f[k] = f2bf(v);
                }
                f[8] = f2bf(sil);
            }
        }
        if (t < KPAD - KRED) LS[KRED + t] = 0;   // K padding
        __syncthreads();
        uint4* dst = (uint4*)(A + (size_t)b * KPAD);
        const uint4* srcv = (const uint4*)LS;
#pragma unroll
        for (int j = 0; j < 4; ++j) {            // 7168 ushorts = 896 x 16B
            int idx = j * 256 + t;
            if (idx < 896) dst[idx] = srcv[idx];
        }
    } else {
        const int blk = blockIdx.x - BATCH;      // 0..489
        const int h = blk / 49, ic = blk % 49;
        const int o = t & 63, iq = t >> 6;
#pragma unroll
        for (int ip = 0; ip < 4; ++ip) {
            int il = iq * 4 + ip;                // 0..15
            int i = ic * 16 + il;
            int hi = h * IN_DIM + i;
            float lm  = lmd[hi];
            float spv = ssp[(size_t)hi * 64 + o] * lm;
            float bse = sb [(size_t)hi * 64 + o] * lm;
            const float* cp = coef + ((size_t)hi * 64 + o) * 8;   // 32B contiguous, lanes span o
            unsigned short* d = LS + o * 144 + il * 9;
#pragma unroll
            for (int k = 0; k < 8; ++k) d[k] = f2bf(cp[k] * spv);
            d[8] = f2bf(bse);
        }
        __syncthreads();
#pragma unroll
        for (int j = 0; j < 5; ++j) {            // 64 rows x 288B = 1152 x 16B
            int idx = j * 256 + t;
            if (idx < 1152) {
                int row = idx / 18, c = idx - row * 18;
                uint4 v = *(const uint4*)(LS + row * 144 + c * 8);
                *(uint4*)(Wt + (size_t)(h * 64 + row) * KPAD + ic * 144 + c * 8) = v;
            }
        }
        if (ic == 48) {                          // zero K-pad: 64 rows x 224B = 896 x 16B
            uint4 z = uint4{0, 0, 0, 0};
#pragma unroll
            for (int j = 0; j < 4; ++j) {
                int idx = j * 256 + t;
                if (idx < 896) {
                    int row = idx / 14, c = idx - row * 14;
                    *(uint4*)(Wt + (size_t)(h * 64 + row) * KPAD + KRED + c * 8) = z;
                }
            }
        }
    }
}

// ---- kernel 2: GEMM 1024x640x7168 bf16 MFMA, tile 128x64, 4 waves, split-K=8 ----
// Round-4 structure; bf16 partials P.
__global__ __launch_bounds__(256) void gemm_kernel(const unsigned short* __restrict__ A,
                                                   const unsigned short* __restrict__ Wt,
                                                   unsigned short* __restrict__ P) {
    __shared__ unsigned short As[2 * ABUF];      // 32 KB
    __shared__ unsigned short Bs[2 * BBUF];      // 16 KB
    const int p = blockIdx.x;
    const int sk = p & 7;                        // XCD x owns split-K slice x
    const int rem = p >> 3;
    const int bn = rem >> 3;                     // 0..9
    const int bm = rem & 7;                      // 0..7
    const int tid = threadIdx.x;
    const int w = tid >> 6, l = tid & 63;

    v4f acc[2][4];
#pragma unroll
    for (int a = 0; a < 2; ++a)
#pragma unroll
        for (int b = 0; b < 4; ++b) acc[a][b] = v4f{0.f, 0.f, 0.f, 0.f};

    const int k0 = sk * KCHUNK;
    const int arow0 = w * 32 + (l & 15);
    const int kkb = (l >> 4) * 16;               // byte offset of lane's 16B within 128B row

#define STAGE(buf, kc)                                                                   \
    {                                                                                    \
        _Pragma("unroll")                                                                \
        for (int r = 0; r < 4; ++r) {            /* A: 128 rows x 128B = 1024 chunks */  \
            int L = r * 256 + tid;                                                       \
            int row = L >> 3, scc = ((L & 7) ^ (row & 7)) * 8;                           \
            __builtin_amdgcn_global_load_lds(                                            \
                (const __attribute__((address_space(1))) void*)(A +                      \
                    (size_t)(bm * BM + row) * KPAD + (kc) + scc),                        \
                (__attribute__((address_space(3))) void*)(As + (buf) * ABUF +            \
                    (r * 256 + w * 64) * 8), 16, 0, 0);                                  \
        }                                                                                \
        _Pragma("unroll")                                                                \
        for (int r = 0; r < 2; ++r) {            /* B: 64 rows x 128B = 512 chunks */    \
            int L = r * 256 + tid;                                                       \
            int row = L >> 3, scc = ((L & 7) ^ (row & 7)) * 8;                           \
            __builtin_amdgcn_global_load_lds(                                            \
                (const __attribute__((address_space(1))) void*)(Wt +                     \
                    (size_t)(bn * BN + row) * KPAD + (kc) + scc),                        \
                (__attribute__((address_space(3))) void*)(Bs + (buf) * BBUF +            \
                    (r * 256 + w * 64) * 8), 16, 0, 0);                                  \
        }                                                                                \
    }

#define COMPUTE(buf)                                                                     \
    {                                                                                    \
        const char* Ab = (const char*)(As + (buf) * ABUF);                               \
        const char* Bb = (const char*)(Bs + (buf) * BBUF);                               \
        _Pragma("unroll")                                                                \
        for (int ks = 0; ks < 2; ++ks) {                                                 \
            v8bf af[2], bfr[4];                                                          \
            _Pragma("unroll")                                                            \
            for (int f = 0; f < 2; ++f) {                                                \
                int ar = arow0 + f * 16;                                                 \
                af[f] = *(const v8bf*)(Ab + ((ar * 128 + ks * 64 + kkb) ^ ((ar & 7) << 4))); \
            }                                                                            \
            _Pragma("unroll")                                                            \
            for (int g = 0; g < 4; ++g) {                                                \
                int br = g * 16 + (l & 15);                                              \
                bfr[g] = *(const v8bf*)(Bb + ((br * 128 + ks * 64 + kkb) ^ ((br & 7) << 4))); \
            }                                                                            \
            _Pragma("unroll")                                                            \
            for (int fi = 0; fi < 2; ++fi)                                               \
                _Pragma("unroll")                                                        \
                for (int fj = 0; fj < 4; ++fj)                                           \
                    acc[fi][fj] = __builtin_amdgcn_mfma_f32_16x16x32_bf16(               \
                        af[fi], bfr[fj], acc[fi][fj], 0, 0, 0);                          \
        }                                                                                \
    }

    STAGE(0, k0);
    __syncthreads();
#pragma unroll 1
    for (int t2 = 0; t2 < KITERS / 2; ++t2) {    // 7 double-iterations
        STAGE(1, k0 + (2 * t2 + 1) * BK);
        COMPUTE(0);
        __syncthreads();
        if (t2 + 1 < KITERS / 2) STAGE(0, k0 + (2 * t2 + 2) * BK);
        COMPUTE(1);
        __syncthreads();
    }
#undef STAGE
#undef COMPUTE

    // C/D layout: col = lane&15, row = 4*(lane>>4)+r   [measured m89]
    const int rowb = bm * BM + w * 32 + 4 * (l >> 4);
    const int colb = bn * BN + (l & 15);
#pragma unroll
    for (int fi = 0; fi < 2; ++fi)
#pragma unroll
        for (int fj = 0; fj < 4; ++fj)
#pragma unroll
            for (int r = 0; r < 4; ++r)
                P[((size_t)sk * BATCH + rowb + fi * 16 + r) * NCOL + colb + fj * 16] =
                    f2bf(acc[fi][fj][r]);
}

// ---- kernel 3 (v2): block per (16 batch rows x head). Vectorized P reads, LDS MLP ----
__global__ __launch_bounds__(256) void epi_kernel(const unsigned short* __restrict__ P,
                                                  const float* __restrict__ W1,
                                                  const float* __restrict__ b1,
                                                  const float* __restrict__ W2,
                                                  const float* __restrict__ b2,
                                                  float* __restrict__ out) {
    __shared__ float h1s[16][64];                // 4 KB
    __shared__ float W1s[64 * 32];               // 8 KB
    const int t = threadIdx.x;
    const int b0 = blockIdx.x * 16;              // grid.x = 64
    const int h = blockIdx.y;

    // load W1[h]: 2048 floats = 512 float4
    {
        const float4* src = (const float4*)(W1 + (size_t)h * 2048);
        float4* dst = (float4*)W1s;
        dst[t] = src[t];
        dst[256 + t] = src[256 + t];
    }
    // phase 1: thread (row = t>>4, oq = t&15) sums 4 o-values over 8 split-K slices
    {
        const int row = t >> 4, oq = t & 15;     // o = oq*4 .. +3
        float y0 = 0.f, y1 = 0.f, y2 = 0.f, y3 = 0.f;
        size_t base = (size_t)(b0 + row) * NCOL + h * 64 + oq * 4;
#pragma unroll
        for (int s = 0; s < SK; ++s) {
            uint2 v = *(const uint2*)(P + (size_t)s * BATCH * NCOL + base);
            y0 += bf2f((unsigned short)(v.x & 0xffff));
            y1 += bf2f((unsigned short)(v.x >> 16));
            y2 += bf2f((unsigned short)(v.y & 0xffff));
            y3 += bf2f((unsigned short)(v.y >> 16));
        }
        h1s[row][oq * 4 + 0] = tanhf(y0);
        h1s[row][oq * 4 + 1] = tanhf(y1);
        h1s[row][oq * 4 + 2] = tanhf(y2);
        h1s[row][oq * 4 + 3] = tanhf(y3);
    }
    __syncthreads();
    // phase 2: thread (d = t&31, rq = t>>5) handles rows rq, rq+8
    {
        const int d = t & 31, rq = t >> 5;
        const float w2v = W2[h * 32 + d];
        const float b1v = b1[h * 32 + d];
        const float b2v = b2[h];
#pragma unroll
        for (int pass = 0; pass < 2; ++pass) {
            int row = pass * 8 + rq;
            float a2 = 0.f;
#pragma unroll 8
            for (int o = 0; o < 64; ++o) a2 += h1s[row][o] * W1s[o * 32 + d];
            float h2 = tanhf(a2 + b1v);
            float pp = h2 * w2v;
#pragma unroll
            for (int off = 16; off; off >>= 1) pp += __shfl_xor(pp, off);
            if (d == 0) out[(b0 + row) * NHEADS + h] = pp + b2v;
        }
    }
}

extern "C" void kernel_launch(void* const* d_in, const int* in_sizes, int n_in,
                              void* d_out, int out_size, void* d_ws, size_t ws_size,
                              hipStream_t stream) {
    const float* x    = (const float*)d_in[0];
    const float* coef = (const float*)d_in[1];
    const float* sb   = (const float*)d_in[2];
    const float* ssp  = (const float*)d_in[3];
    const float* lmd  = (const float*)d_in[4];
    const float* W1   = (const float*)d_in[5];
    const float* b1   = (const float*)d_in[6];
    const float* W2   = (const float*)d_in[7];
    const float* b2   = (const float*)d_in[8];
    float* out = (float*)d_out;

    unsigned short* Af = (unsigned short*)d_ws;                  // 1024*7168*2 = 14.68 MB
    unsigned short* Wt = Af + (size_t)BATCH * KPAD;              // 640*7168*2  =  9.18 MB
    unsigned short* P  = Wt + (size_t)NCOL * KPAD;               // 8*1024*640*2 = 10.49 MB

    hipLaunchKernelGGL(prep_kernel, dim3(BATCH + 490), dim3(256), 0, stream,
                       x, coef, sb, ssp, lmd, Af, Wt);
    hipLaunchKernelGGL(gemm_kernel, dim3(640), dim3(256), 0, stream, Af, Wt, P);
    hipLaunchKernelGGL(epi_kernel, dim3(64, NHEADS), dim3(256), 0, stream,
                       P, W1, b1, W2, b2, out);
}